// Round 8
// baseline (383.325 us; speedup 1.0000x reference)
//
#include <hip/hip_runtime.h>
#include <hip/hip_bf16.h>
#include <stdint.h>

// Problem constants
#define BQ 128    // batch
#define NJ 512    // input capsules j
#define DD 300    // input dim
#define NC 10     // num_capsule i
#define DC 64     // dim_capsule k
#define MM 640    // NC*DC
#define KP 320    // K padded (mult of 64)

typedef __attribute__((ext_vector_type(8))) short short8;
typedef __attribute__((ext_vector_type(4))) short short4v;
typedef __attribute__((ext_vector_type(4))) float f32x4;

__device__ __forceinline__ float bf2f(ushort u) { return __uint_as_float((uint)u << 16); }
__device__ __forceinline__ ushort f2bf(float f) {
    __hip_bfloat16 h = __float2bfloat16(f);
    return *(ushort*)&h;
}
// 8-B-aligned LDS read of 8 bf16 (xs rows are 600 B pitch: 16-B alignment not guaranteed)
__device__ __forceinline__ short8 lds_frag8(const ushort* p) {
    union { short4v h[2]; short8 v; } u;
    u.h[0] = *(const short4v*)(p);
    u.h[1] = *(const short4v*)(p + 4);
    return u.v;
}

// ---------------- tiny utility kernels ----------------

__global__ __launch_bounds__(256)
void k_zf(uint4* __restrict__ p, int n4) {          // zero wot+cnt+flag region
    int g = blockIdx.x * 256 + threadIdx.x;
    if (g < n4) p[g] = make_uint4(0, 0, 0, 0);
}

__global__ __launch_bounds__(256)
void k_cast_w(const float* __restrict__ W, ushort* __restrict__ wt) {
    int idx = blockIdx.x * 256 + threadIdx.x;        // 204800
    int m = idx / KP, k = idx - m * KP;
    float v = (k < DD) ? W[(size_t)k * MM + m] : 0.f;
    wt[idx] = f2bf(v);
}

// ---------------- fused persistent routing kernel ----------------
// Grid 1024 = (b, jo 0..7), 320 thr, LDS = 38400 (xs) + 2560 (scr) = 40960 B
// -> 4 blocks/CU -> ALL blocks resident (runtime-verified) -> per-b spin-sync
// among 8 sibling blocks is deadlock-free. x staged to LDS ONCE; iterations
// 1..4 read only LDS + tiny L2 (wot 12.8KB/b, wt/W shared).
// Sync protocol per iteration: partial-write -> release cnt[b][it]; all 8 poll
// cnt==8 (acquire) -> distributed combine (block jo owns i=jo, +i=jo+8 if jo<2)
// -> wot write -> release flag[b]++; next iter polls flag >= 8*it.

__global__ __launch_bounds__(320, 5)
void k_main(const float* __restrict__ x, const float* __restrict__ W,
            const ushort* __restrict__ wt, ushort* __restrict__ wot,
            float* __restrict__ pcx, int* __restrict__ cnt, int* __restrict__ flag,
            float* __restrict__ out) {
    __shared__ __align__(16) ushort xs[64 * DD];     // 38400 B, pitch 300 u16
    __shared__ __align__(16) float scr[640];         // 2560 B: c / cx rows / ov

    const int t = threadIdx.x, blk = blockIdx.x;
    const int b = blk >> 3, jo = blk & 7;
    const int w = t >> 6, lane = t & 63, quad = lane >> 4, r = lane & 15;

    if (t < 16) scr[t] = 0.f;   // bl row-63 B-frag overreach lands in scr[0..9]

    // ---- stage x slice (b, jo*64..+63, 0..299) f32 -> xs bf16 (read x ONCE)
    {
        const float4* src4 = (const float4*)(x + (size_t)(b * NJ + jo * 64) * DD);
#pragma unroll
        for (int s = 0; s < 15; ++s) {
            int g = t + s * 320;                     // 4800 float4 total
            float4 v = src4[g];
            union { ushort u[4]; uint2 q; } o;
            o.u[0] = f2bf(v.x); o.u[1] = f2bf(v.y);
            o.u[2] = f2bf(v.z); o.u[3] = f2bf(v.w);
            *(uint2*)(xs + g * 4) = o.q;
        }
    }
    __syncthreads();

    float* pp = pcx + (size_t)blk * NC * KP;
    const int i1 = jo, i2 = (jo < 2) ? jo + 8 : -1;

    for (int it = 0; it < 5; ++it) {
        if (it > 0) {
            if (t == 0) {
                while (__hip_atomic_load(&flag[b], __ATOMIC_ACQUIRE,
                                         __HIP_MEMORY_SCOPE_AGENT) < 8 * it)
                    __builtin_amdgcn_s_sleep(2);
            }
            __syncthreads();

            // ---- bl GEMM (waves 0..3, 16 j each) + softmax -> c in scr[i*64+j]
            if (w < 4) {
                f32x4 acc = {0.f,0.f,0.f,0.f}, ac2 = {0.f,0.f,0.f,0.f};
                const ushort* aph = wot + ((size_t)(b*2+0)*16 + r) * KP + quad * 8;
                const ushort* apl = wot + ((size_t)(b*2+1)*16 + r) * KP + quad * 8;
                const ushort* bp  = xs + (w*16 + r) * DD + quad * 8;
#pragma unroll
                for (int ks = 0; ks < 10; ++ks) {
                    short8 bf = lds_frag8(bp + ks * 32);   // d>=300 garbage x A-zero = 0
                    short8 ah = *(const short8*)(aph + ks * 32);
                    short8 al = *(const short8*)(apl + ks * 32);
                    acc = __builtin_amdgcn_mfma_f32_16x16x32_bf16(ah, bf, acc, 0, 0, 0);
                    ac2 = __builtin_amdgcn_mfma_f32_16x16x32_bf16(al, bf, ac2, 0, 0, 0);
                }
                float blv[4];
#pragma unroll
                for (int p = 0; p < 4; ++p) blv[p] = acc[p] + ac2[p];
                float mx;
                if (quad < 2)       mx = fmaxf(fmaxf(blv[0], blv[1]), fmaxf(blv[2], blv[3]));
                else if (quad == 2) mx = fmaxf(blv[0], blv[1]);
                else                mx = -1e30f;
                mx = fmaxf(mx, __shfl_xor(mx, 16, 64));
                mx = fmaxf(mx, __shfl_xor(mx, 32, 64));
                float e0 = (quad < 3) ? __expf(blv[0] - mx) : 0.f;
                float e1 = (quad < 3) ? __expf(blv[1] - mx) : 0.f;
                float e2 = (quad < 2) ? __expf(blv[2] - mx) : 0.f;
                float e3 = (quad < 2) ? __expf(blv[3] - mx) : 0.f;
                float ss = e0 + e1 + e2 + e3;
                ss += __shfl_xor(ss, 16, 64);
                ss += __shfl_xor(ss, 32, 64);
                float inv = 1.f / ss;
                int j = w * 16 + r;
                if (quad < 2) {
                    scr[(quad*4+0)*64 + j] = e0 * inv;
                    scr[(quad*4+1)*64 + j] = e1 * inv;
                    scr[(quad*4+2)*64 + j] = e2 * inv;
                    scr[(quad*4+3)*64 + j] = e3 * inv;
                } else if (quad == 2) {
                    scr[8*64 + j] = e0 * inv;
                    scr[9*64 + j] = e1 * inv;
                }
            }
            __syncthreads();
        }

        // ---- Cx partial (thread owns d = t); it==0: c uniform = 0.1
        if (t < DD) {
            float cxa[10];
            if (it == 0) {
                float s = 0.f;
#pragma unroll 8
                for (int j = 0; j < 64; ++j) s += bf2f(xs[j * DD + t]);
                s *= 0.1f;
#pragma unroll
                for (int i = 0; i < 10; ++i) cxa[i] = s;
            } else {
#pragma unroll
                for (int i = 0; i < 10; ++i) cxa[i] = 0.f;
#pragma unroll 4
                for (int j = 0; j < 64; j += 2) {
                    float x0 = bf2f(xs[j * DD + t]);
                    float x1 = bf2f(xs[(j + 1) * DD + t]);
#pragma unroll
                    for (int i = 0; i < 10; ++i) {
                        float2 cc = *(const float2*)&scr[i * 64 + j];
                        cxa[i] += cc.x * x0 + cc.y * x1;
                    }
                }
            }
#pragma unroll
            for (int i = 0; i < 10; ++i) pp[i * KP + t] = cxa[i];
        }
        __syncthreads();
        if (t == 0) {
            __threadfence();
            __hip_atomic_fetch_add(&cnt[b*5+it], 1, __ATOMIC_RELEASE, __HIP_MEMORY_SCOPE_AGENT);
            while (__hip_atomic_load(&cnt[b*5+it], __ATOMIC_ACQUIRE,
                                     __HIP_MEMORY_SCOPE_AGENT) < 8)
                __builtin_amdgcn_s_sleep(2);
        }
        __syncthreads();

        // ---- distributed combine: (a) cx rows for owned i's into scr
        {
            float v1 = 0.f, v2 = 0.f;
            if (t < DD) {
                const float* base = pcx + (size_t)(b * 8) * NC * KP + t;
#pragma unroll
                for (int jb = 0; jb < 8; ++jb) v1 += base[(size_t)jb * NC * KP + i1 * KP];
                if (i2 >= 0) {
#pragma unroll
                    for (int jb = 0; jb < 8; ++jb) v2 += base[(size_t)jb * NC * KP + i2 * KP];
                }
            }
            scr[t] = v1;                              // cx(i1)[d], zeros for d>=300
            if (i2 >= 0) scr[320 + t] = v2;           // cx(i2)[d]
        }
        __syncthreads();

        // ---- (b) po + squash: wave 0 -> i1, wave 1 -> i2; lane = k
        if (w == 0 || (w == 1 && i2 >= 0)) {
            int ii = (w == 0) ? i1 : i2;
            const float* cxr = scr + w * 320;
            const ushort* wr = wt + (size_t)(ii * 64 + lane) * KP;
            float po = 0.f;
#pragma unroll
            for (int g = 0; g < 40; ++g) {
                union { uint4 q; ushort u[8]; } wv;
                wv.q = *(const uint4*)(wr + g * 8);
                const float* cc = cxr + g * 8;
#pragma unroll
                for (int e = 0; e < 8; ++e) po += bf2f(wv.u[e]) * cc[e];
            }
            float sq = po * po;
#pragma unroll
            for (int m = 32; m >= 1; m >>= 1) sq += __shfl_xor(sq, m, 64);
            float ov = po * rsqrtf(sq + 1e-7f);
            if (it == 4) out[(size_t)b * MM + ii * 64 + lane] = ov;
            else         scr[w * 64 + lane] = ov;     // ov(i1)->scr[0..63], ov(i2)->scr[64..127]
        }
        if (it == 4) return;
        __syncthreads();

        // ---- (c) Wo slices for owned i's: Wo[i][d] = sum_k W[d][i*64+k]*ov[k]
        if (t < DD) {
            const float4* wr4 = (const float4*)(W + (size_t)t * MM + i1 * 64);
            const float4* ov4 = (const float4*)(scr);
            float s = 0.f;
#pragma unroll
            for (int kk = 0; kk < 16; ++kk) {
                float4 a = wr4[kk]; float4 o = ov4[kk];
                s += a.x * o.x + a.y * o.y + a.z * o.z + a.w * o.w;
            }
            ushort hu = f2bf(s);
            wot[((size_t)(b*2+0)*16 + i1) * KP + t] = hu;
            wot[((size_t)(b*2+1)*16 + i1) * KP + t] = f2bf(s - bf2f(hu));
            if (i2 >= 0) {
                const float4* wr42 = (const float4*)(W + (size_t)t * MM + i2 * 64);
                const float4* ov42 = (const float4*)(scr + 64);
                float s2 = 0.f;
#pragma unroll
                for (int kk = 0; kk < 16; ++kk) {
                    float4 a = wr42[kk]; float4 o = ov42[kk];
                    s2 += a.x * o.x + a.y * o.y + a.z * o.z + a.w * o.w;
                }
                ushort hu2 = f2bf(s2);
                wot[((size_t)(b*2+0)*16 + i2) * KP + t] = hu2;
                wot[((size_t)(b*2+1)*16 + i2) * KP + t] = f2bf(s2 - bf2f(hu2));
            }
        }
        __syncthreads();
        if (t == 0) {
            __threadfence();
            __hip_atomic_fetch_add(&flag[b], 1, __ATOMIC_RELEASE, __HIP_MEMORY_SCOPE_AGENT);
        }
    }
}

// ================= discrete fallback (round-7 path, verified passing) =================

__global__ __launch_bounds__(256)
void k_cast_x(const float* __restrict__ x, ushort* __restrict__ xb) {
    int g = blockIdx.x * 256 + threadIdx.x;
    int row = g / 40, cg2 = g - row * 40;
    const float* src = x + (size_t)row * DD + cg2 * 8;
    float4 a = make_float4(0.f, 0.f, 0.f, 0.f), b4 = a;
    if (cg2 < 37) { a = *(const float4*)src; b4 = *(const float4*)(src + 4); }
    else if (cg2 == 37) { a = *(const float4*)src; }
    union { ushort u[8]; uint4 v; } o;
    float f[8] = {a.x, a.y, a.z, a.w, b4.x, b4.y, b4.z, b4.w};
#pragma unroll
    for (int e = 0; e < 8; ++e) o.u[e] = f2bf(f[e]);
    *(uint4*)(xb + (size_t)row * KP + cg2 * 8) = o.v;
}

#define XP 344

template<int FIRST>
__global__ __launch_bounds__(320)
void k_pass(const ushort* __restrict__ xb, const ushort* __restrict__ wot,
            float* __restrict__ pcx) {
    __shared__ __align__(16) ushort xs[64 * XP];
    __shared__ __align__(16) float c_lds[10][68];
    const int t = threadIdx.x, w = t >> 6, lane = t & 63;
    const int quad = lane >> 4, r = lane & 15;
    const int blk = blockIdx.x, b = blk >> 3, jo = blk & 7;
    {
        const uint4* gsrc = (const uint4*)(xb + (size_t)(b * NJ + jo * 64) * KP);
        int idx = t;
#pragma unroll
        for (int s = 0; s < 8; ++s, idx += 320) {
            int row = idx / 40, col = idx - row * 40;
            *(uint4*)(xs + row * XP + col * 8) = gsrc[row * 40 + col];
        }
    }
    __syncthreads();
    if (!FIRST && w < 4) {
        f32x4 acc = {0.f,0.f,0.f,0.f}, ac2 = {0.f,0.f,0.f,0.f};
        const ushort* aph = wot + ((size_t)(b*2+0)*16 + r) * KP + quad * 8;
        const ushort* apl = aph + 16 * KP;
        const ushort* bp  = xs + (w * 16 + r) * XP + quad * 8;
#pragma unroll
        for (int ks = 0; ks < 10; ++ks) {
            short8 bf = *(const short8*)(bp + ks * 32);
            short8 ah = *(const short8*)(aph + ks * 32);
            short8 al = *(const short8*)(apl + ks * 32);
            acc = __builtin_amdgcn_mfma_f32_16x16x32_bf16(ah, bf, acc, 0, 0, 0);
            ac2 = __builtin_amdgcn_mfma_f32_16x16x32_bf16(al, bf, ac2, 0, 0, 0);
        }
        float blv[4];
#pragma unroll
        for (int p = 0; p < 4; ++p) blv[p] = acc[p] + ac2[p];
        float mx;
        if (quad < 2)       mx = fmaxf(fmaxf(blv[0], blv[1]), fmaxf(blv[2], blv[3]));
        else if (quad == 2) mx = fmaxf(blv[0], blv[1]);
        else                mx = -1e30f;
        mx = fmaxf(mx, __shfl_xor(mx, 16, 64));
        mx = fmaxf(mx, __shfl_xor(mx, 32, 64));
        float e0 = (quad < 3) ? __expf(blv[0] - mx) : 0.f;
        float e1 = (quad < 3) ? __expf(blv[1] - mx) : 0.f;
        float e2 = (quad < 2) ? __expf(blv[2] - mx) : 0.f;
        float e3 = (quad < 2) ? __expf(blv[3] - mx) : 0.f;
        float ss = e0 + e1 + e2 + e3;
        ss += __shfl_xor(ss, 16, 64);
        ss += __shfl_xor(ss, 32, 64);
        float inv = 1.f / ss;
        int j = w * 16 + r;
        if (quad < 2) {
            c_lds[quad*4+0][j] = e0 * inv; c_lds[quad*4+1][j] = e1 * inv;
            c_lds[quad*4+2][j] = e2 * inv; c_lds[quad*4+3][j] = e3 * inv;
        } else if (quad == 2) { c_lds[8][j] = e0 * inv; c_lds[9][j] = e1 * inv; }
    }
    __syncthreads();
    float cxa[10];
    if (FIRST) {
        float s = 0.f;
#pragma unroll 8
        for (int j = 0; j < 64; ++j) s += bf2f(xs[j * XP + t]);
        s *= 0.1f;
#pragma unroll
        for (int i = 0; i < 10; ++i) cxa[i] = s;
    } else {
#pragma unroll
        for (int i = 0; i < 10; ++i) cxa[i] = 0.f;
#pragma unroll 4
        for (int j = 0; j < 64; j += 2) {
            float x0 = bf2f(xs[j * XP + t]);
            float x1 = bf2f(xs[(j + 1) * XP + t]);
#pragma unroll
            for (int i = 0; i < 10; ++i) {
                float2 cc = *(const float2*)&c_lds[i][j];
                cxa[i] += cc.x * x0 + cc.y * x1;
            }
        }
    }
    float* pout = pcx + (size_t)blk * 10 * KP;
#pragma unroll
    for (int i = 0; i < 10; ++i) pout[i * KP + t] = cxa[i];
}

template<int MODE>
__global__ __launch_bounds__(256)
void k_out(const float* __restrict__ src, const float* __restrict__ W,
           const ushort* __restrict__ wt, ushort* __restrict__ wot,
           float* __restrict__ dst) {
    __shared__ __align__(16) float cx[KP];
    __shared__ __align__(16) float red[4 * 64];
    __shared__ __align__(16) float outl[DC];
    const int blk = blockIdx.x;
    const int b = blk / 10, i = blk - b * 10;
    const int t = threadIdx.x, w = t >> 6, lane = t & 63;
    for (int d = t; d < KP; d += 256) {
        const float* pp = src + (size_t)b * 8 * 10 * KP + (size_t)i * KP + d;
        float v = 0.f;
#pragma unroll
        for (int jb = 0; jb < 8; ++jb) v += pp[(size_t)jb * 10 * KP];
        cx[d] = v;
    }
    __syncthreads();
    {
        const ushort* wr = wt + (size_t)(i * 64 + lane) * KP + w * 80;
        const float* cr = cx + w * 80;
        float pp = 0.f;
#pragma unroll
        for (int kk = 0; kk < 10; ++kk) {
            union { uint4 q; ushort u[8]; } wv;
            wv.q = *(const uint4*)(wr + kk * 8);
#pragma unroll
            for (int e = 0; e < 8; ++e) pp += bf2f(wv.u[e]) * cr[kk * 8 + e];
        }
        red[w * 64 + lane] = pp;
    }
    __syncthreads();
    if (w == 0) {
        float po = red[lane] + red[64 + lane] + red[128 + lane] + red[192 + lane];
        float sq = po * po;
#pragma unroll
        for (int m = 32; m >= 1; m >>= 1) sq += __shfl_xor(sq, m, 64);
        float ov = po * rsqrtf(sq + 1e-7f);
        if (MODE == 2) dst[(size_t)b * MM + i * 64 + lane] = ov;
        else           outl[lane] = ov;
    }
    if (MODE == 2) return;
    __syncthreads();
    for (int d = t; d < KP; d += 256) {
        float s = 0.f;
        if (d < DD) {
            const float4* wr4 = (const float4*)(W + (size_t)d * MM + i * 64);
            const float4* ol4 = (const float4*)outl;
#pragma unroll
            for (int kk = 0; kk < 16; ++kk) {
                float4 a = wr4[kk]; float4 o = ol4[kk];
                s += a.x * o.x + a.y * o.y + a.z * o.z + a.w * o.w;
            }
        }
        ushort hu = f2bf(s);
        wot[((size_t)(b*2+0)*16 + i) * KP + d] = hu;
        wot[((size_t)(b*2+1)*16 + i) * KP + d] = f2bf(s - bf2f(hu));
    }
}

// ================= launch =================

extern "C" void kernel_launch(void* const* d_in, const int* in_sizes, int n_in,
                              void* d_out, int out_size, void* d_ws, size_t ws_size,
                              hipStream_t stream) {
    const float* x = (const float*)d_in[0];   // [128,512,300]
    const float* W = (const float*)d_in[1];   // [1,300,640]
    float* out = (float*)d_out;               // [128,10,64]
    char* ws = (char*)d_ws;

    // one-time: verify full co-residency of the fused kernel (deadlock guard)
    static int fused = -1;
    if (fused == -1) {
        int nb = 0, ncu = 0;
        hipError_t e = hipOccupancyMaxActiveBlocksPerMultiprocessor(
            &nb, (const void*)k_main, 320, 0);
        hipDeviceProp_t prop;
        if (hipGetDeviceProperties(&prop, 0) == hipSuccess) ncu = prop.multiProcessorCount;
        fused = (e == hipSuccess && nb > 0 && (long)nb * ncu >= BQ * 8) ? 1 : 0;
    }

    if (fused) {
        size_t o = 0;
        ushort* wot = (ushort*)(ws + o); o += (size_t)BQ * 2 * 16 * KP * 2;  // 2,621,440
        int*    cnt = (int*)(ws + o);    o += (size_t)BQ * 5 * 4;            // 2,560
        int*    flg = (int*)(ws + o);    o += (size_t)BQ * 4;                // 512
        ushort* wt  = (ushort*)(ws + o); o += (size_t)MM * KP * 2;           // 409,600
        float*  pcx = (float*)(ws + o);  o += (size_t)BQ * 8 * NC * KP * 4;  // 13.1 MB

        const int n4 = (int)((2621440 + 2560 + 512) / 16);                   // 164,032
        k_zf<<<(n4 + 255) / 256, 256, 0, stream>>>((uint4*)wot, n4);
        k_cast_w<<<(MM * KP) / 256, 256, 0, stream>>>(W, wt);
        k_main<<<BQ * 8, 320, 0, stream>>>(x, W, wt, wot, pcx, cnt, flg, out);
    } else {
        // discrete round-7 path (no co-residency assumptions)
        size_t o = 0;
        ushort* xb  = (ushort*)(ws + o); o += (size_t)BQ * NJ * KP * 2;
        ushort* wt  = (ushort*)(ws + o); o += (size_t)MM * KP * 2;
        ushort* wot = (ushort*)(ws + o); o += (size_t)BQ * 2 * 16 * KP * 2;
        float*  pcx = (float*)(ws + o);  o += (size_t)BQ * 8 * NC * KP * 4;

        k_cast_x<<<(BQ * NJ * 40) / 256, 256, 0, stream>>>(x, xb);
        k_cast_w<<<(MM * KP) / 256, 256, 0, stream>>>(W, wt);
        k_pass<1><<<BQ * 8, 320, 0, stream>>>(xb, wot, pcx);
        k_out<1><<<BQ * NC, 256, 0, stream>>>(pcx, W, wt, wot, nullptr);
        for (int it = 1; it <= 4; ++it) {
            k_pass<0><<<BQ * 8, 320, 0, stream>>>(xb, wot, pcx);
            if (it < 4) k_out<1><<<BQ * NC, 256, 0, stream>>>(pcx, W, wt, wot, nullptr);
            else        k_out<2><<<BQ * NC, 256, 0, stream>>>(pcx, W, wt, wot, out);
        }
    }
}